// Round 2
// baseline (490.305 us; speedup 1.0000x reference)
//
#include <hip/hip_runtime.h>

// Workspace layout (~232 MiB):
//   [0, 256K)      a_scores  fp32 [2][32][1024]   (zeroed, atomic accum)
//   [256K, 512K)   softmax w fp32 [2][32][1024]
//   [512K, 640K)   acc       fp32 [2][32][512]    (zeroed; seqmean + vector)
//   [768K, 774K)   bias_cat  fp32 [1536]
//   [1M, 2.5M)     Wt bf16   [1536][512]  (Wt[w*512+n][k] = W_w[k][n])
//   [4M, 36M)      Xb2 bf16  [32768][512]  (seq2 converted)
//   [40M, 232M)    qkv bf16  [6][32768][512]  slots: q1,k1,v1,q2,k2,v2
// R1: XCD chunked swizzle on both GEMMs -> FETCH 274->77MB (confirmed), but
// time flat: m97 2-barrier structure is schedule-bound (678 TF, MfmaUtil 29%).
// R2: port both GEMMs to 256x256 / BK=64 / 8-wave / 8-phase schedule
// (T3+T4) + st_16x32 LDS XOR swizzle (T2, both-sides: pre-swizzled global
// source + swizzled ds_read) + setprio around MFMA clusters (T5).
// Race-free pipelining proof: 2 tile-buffers; odd tile staged phases 1-2,
// drained at phase-4 __syncthreads (2-3 phases of cover); next even tile
// staged phases 5-6, drained at phase-8 __syncthreads. A buffer is only
// written between its last read (phase 4 / phase 8 sync) and next drain.

typedef __bf16 bf16x8_t __attribute__((ext_vector_type(8)));
typedef float f32x4_t __attribute__((ext_vector_type(4)));

__device__ __forceinline__ unsigned short f2bf(float f) {
    union { float f; unsigned int u; } c; c.f = f;
    unsigned int u = c.u;
    unsigned int r = (u + 0x7FFFu + ((u >> 16) & 1u)) >> 16;  // RNE
    return (unsigned short)r;
}
__device__ __forceinline__ float bf2f(unsigned short h) {
    union { unsigned int u; float f; } c; c.u = ((unsigned int)h) << 16;
    return c.f;
}
__device__ __forceinline__ void gl2lds16(const void* g, void* l) {
    __builtin_amdgcn_global_load_lds(
        (const __attribute__((address_space(1))) void*)g,
        (__attribute__((address_space(3))) void*)l, 16, 0, 0);
}
__device__ __forceinline__ float fast_tanh(float x) {
    float e = __expf(2.f * x);                       // inf for large x -> tanh=1
    return 1.f - 2.f * __builtin_amdgcn_rcpf(e + 1.f);
}

// ---- 256x64 operand tile stage: 4 x global_load_lds(16B) per thread. ----
// LDS linear [row][64k]; source k pre-swizzled (st_16x32: byte^=((b>>9)&1)<<5
// == elem k ^= ((row>>2)&1)*16) so swizzled ds_read recovers linear data.
__device__ __forceinline__ void stage256(
    const unsigned short* __restrict__ src,  // already includes row0*512
    int k0, unsigned short* dstbase, int wv, int lane)
{
    #pragma unroll
    for (int l = 0; l < 4; ++l) {
        int idx = l * 512 + wv * 64 + lane;   // 0..2047
        int row = idx >> 3;                   // 0..255
        int kc = (idx & 7) * 8;               // elem offset 0..56
        kc ^= ((row >> 2) & 1) << 4;          // inverse-swizzle the SOURCE
        gl2lds16(&src[(size_t)row * 512 + k0 + kc],
                 &dstbase[l * 4096 + wv * 512]);   // wave-uniform dest
    }
}

// ---- one phase: 12 ds_read_b128 -> barrier -> 16 MFMA (setprio) -> close.
// DRAIN=true closes with __syncthreads (vmcnt(0)+lgkmcnt(0)+barrier+fence).
template<bool DRAIN>
__device__ __forceinline__ void phase_mfma(
    const unsigned short* A_, const unsigned short* B_,
    f32x4_t acc[8][4], int mh, int nh, int wr, int wc, int qq, int ln)
{
    bf16x8_t af[4][2], bfr[2][2];
    #pragma unroll
    for (int m = 0; m < 4; ++m) {
        int row = wr * 128 + (mh * 4 + m) * 16 + ln;
        #pragma unroll
        for (int ks = 0; ks < 2; ++ks) {
            int e = (row * 64 + ks * 32 + qq * 8) ^ (((row >> 2) & 1) << 4);
            af[m][ks] = *reinterpret_cast<const bf16x8_t*>(&A_[e]);
        }
    }
    #pragma unroll
    for (int n = 0; n < 2; ++n) {
        int row = wc * 64 + (nh * 2 + n) * 16 + ln;
        #pragma unroll
        for (int ks = 0; ks < 2; ++ks) {
            int e = (row * 64 + ks * 32 + qq * 8) ^ (((row >> 2) & 1) << 4);
            bfr[n][ks] = *reinterpret_cast<const bf16x8_t*>(&B_[e]);
        }
    }
    __builtin_amdgcn_s_barrier();
    __builtin_amdgcn_s_setprio(1);
    #pragma unroll
    for (int m = 0; m < 4; ++m)
        #pragma unroll
        for (int n = 0; n < 2; ++n)
            #pragma unroll
            for (int ks = 0; ks < 2; ++ks)
                acc[mh * 4 + m][nh * 2 + n] =
                    __builtin_amdgcn_mfma_f32_16x16x32_bf16(
                        af[m][ks], bfr[n][ks], acc[mh * 4 + m][nh * 2 + n],
                        0, 0, 0);
    __builtin_amdgcn_s_setprio(0);
    if (DRAIN) __syncthreads();
    else       __builtin_amdgcn_s_barrier();
}

// Shared 8-phase main loop over K=512 (8 tiles of BK=64, 2 per iteration).
#define GEMM256_MAINLOOP(Asrc, Bsrc)                                          \
    stage256(Asrc, 0, &lds[0][0][0], wv, lane);                               \
    stage256(Bsrc, 0, &lds[0][1][0], wv, lane);                               \
    __syncthreads();                                                          \
    _Pragma("unroll")                                                         \
    for (int i = 0; i < 4; ++i) {                                             \
        int kO = (2 * i + 1) * 64;                                            \
        int kE = (2 * i + 2) * 64;                                            \
        /* phases 1-4: compute even tile (buf0); stage odd tile -> buf1 */    \
        stage256(Asrc, kO, &lds[1][0][0], wv, lane);                          \
        phase_mfma<false>(&lds[0][0][0], &lds[0][1][0], acc, 0, 0, wr, wc, qq, ln); \
        stage256(Bsrc, kO, &lds[1][1][0], wv, lane);                          \
        phase_mfma<false>(&lds[0][0][0], &lds[0][1][0], acc, 0, 1, wr, wc, qq, ln); \
        phase_mfma<false>(&lds[0][0][0], &lds[0][1][0], acc, 1, 0, wr, wc, qq, ln); \
        phase_mfma<true >(&lds[0][0][0], &lds[0][1][0], acc, 1, 1, wr, wc, qq, ln); \
        /* phases 5-8: compute odd tile (buf1); stage next even -> buf0 */    \
        if (i < 3) stage256(Asrc, kE, &lds[0][0][0], wv, lane);               \
        phase_mfma<false>(&lds[1][0][0], &lds[1][1][0], acc, 0, 0, wr, wc, qq, ln); \
        if (i < 3) stage256(Bsrc, kE, &lds[0][1][0], wv, lane);               \
        phase_mfma<false>(&lds[1][0][0], &lds[1][1][0], acc, 0, 1, wr, wc, qq, ln); \
        phase_mfma<false>(&lds[1][0][0], &lds[1][1][0], acc, 1, 0, wr, wc, qq, ln); \
        phase_mfma<true >(&lds[1][0][0], &lds[1][1][0], acc, 1, 1, wr, wc, qq, ln); \
    }

// ---------------- Kernel 0: seq fp32 -> bf16, fused seq-mean -------------
__global__ __launch_bounds__(256) void x2bf_kernel(
    const float* __restrict__ src, unsigned short* __restrict__ dst,
    float* __restrict__ accv)
{
    int chunk = blockIdx.x;   // 0..7 (128 rows each)
    int b = blockIdx.y;       // 0..31
    int tid = threadIdx.x, lane = tid & 63, wv = tid >> 6;
    __shared__ float red[4][512];
    float sum[8] = {};
    size_t base = ((size_t)b * 1024 + (size_t)chunk * 128) * 512;
    #pragma unroll 4
    for (int i = 0; i < 32; ++i) {
        int r = i * 4 + wv;
        size_t ro = base + (size_t)r * 512;
        float4 a = *reinterpret_cast<const float4*>(&src[ro + lane * 4]);
        float4 c = *reinterpret_cast<const float4*>(&src[ro + 256 + lane * 4]);
        ushort4 ha; ha.x = f2bf(a.x); ha.y = f2bf(a.y); ha.z = f2bf(a.z); ha.w = f2bf(a.w);
        ushort4 hc; hc.x = f2bf(c.x); hc.y = f2bf(c.y); hc.z = f2bf(c.z); hc.w = f2bf(c.w);
        *reinterpret_cast<ushort4*>(&dst[ro + lane * 4]) = ha;
        *reinterpret_cast<ushort4*>(&dst[ro + 256 + lane * 4]) = hc;
        sum[0] += a.x; sum[1] += a.y; sum[2] += a.z; sum[3] += a.w;
        sum[4] += c.x; sum[5] += c.y; sum[6] += c.z; sum[7] += c.w;
    }
    #pragma unroll
    for (int t = 0; t < 4; ++t) {
        red[wv][lane * 4 + t] = sum[t];
        red[wv][256 + lane * 4 + t] = sum[4 + t];
    }
    __syncthreads();
    #pragma unroll
    for (int j = 0; j < 2; ++j) {
        int col = tid + j * 256;
        float s = red[0][col] + red[1][col] + red[2][col] + red[3][col];
        atomicAdd(&accv[(size_t)b * 512 + col], s * (1.f / 1024.f));
    }
}

// ---------------- Kernel 1: W [k][n] fp32 -> Wt [n][k] bf16 --------------
__global__ __launch_bounds__(256) void wconv_kernel(
    const float* __restrict__ Wq, const float* __restrict__ Wk,
    const float* __restrict__ Wv, unsigned short* __restrict__ Wt)
{
    const float* W = (blockIdx.z == 0) ? Wq : (blockIdx.z == 1) ? Wk : Wv;
    unsigned short* o = Wt + (size_t)blockIdx.z * 512 * 512;
    __shared__ unsigned short t[64][65];
    int k0 = blockIdx.x * 64, n0 = blockIdx.y * 64;
    #pragma unroll
    for (int i = 0; i < 16; ++i) {
        int idx = i * 256 + threadIdx.x;
        int r = idx >> 6, c = idx & 63;
        t[r][c] = f2bf(W[(size_t)(k0 + r) * 512 + n0 + c]);
    }
    __syncthreads();
    #pragma unroll
    for (int i = 0; i < 16; ++i) {
        int idx = i * 256 + threadIdx.x;
        int r = idx >> 6, c = idx & 63;   // r = n, c = k
        o[(size_t)(n0 + r) * 512 + k0 + c] = t[c][r];
    }
}

__global__ __launch_bounds__(512) void biascat_kernel(
    const float* __restrict__ bq, const float* __restrict__ bk,
    const float* __restrict__ bv, float* __restrict__ bc)
{
    int n = threadIdx.x;
    bc[n] = bq[n]; bc[512 + n] = bk[n]; bc[1024 + n] = bv[n];
}

// ------------- Kernel 2: QKV projection GEMM (256^2 8-phase) -------------
// C = relu(X @ [Wq|Wk|Wv] + b) -> bf16 slots. 8 waves 2Mx4N, 128x64/wave.
__global__ __launch_bounds__(512, 2) void qkv_gemm(
    const unsigned short* __restrict__ Xb1, const unsigned short* __restrict__ Xb2,
    const unsigned short* __restrict__ Wt, const float* __restrict__ bias_cat,
    unsigned short* __restrict__ qkv)
{
    __shared__ alignas(16) unsigned short lds[2][2][16384];  // 128 KB

    // bijective chunked XCD swizzle: 1536 blocks, 192/XCD, nt minor
    unsigned int fid = blockIdx.x;
    unsigned int swz = (fid & 7u) * 192u + (fid >> 3);
    int nt = swz % 6u;            // 0..5 (256-wide N tile)
    int mg = swz / 6u;            // 0..255
    int z = mg >> 7;              // which sequence
    int mrow0 = (mg & 127) * 256;
    int n0 = nt * 256;

    const unsigned short* Asrc = (z ? Xb2 : Xb1) + (size_t)mrow0 * 512;
    const unsigned short* Bsrc = Wt + (size_t)n0 * 512;

    int tid = threadIdx.x, lane = tid & 63, wv = tid >> 6;
    int wr = wv >> 2, wc = wv & 3;         // 2M x 4N wave grid
    int qq = lane >> 4, ln = lane & 15;

    f32x4_t acc[8][4] = {};

    GEMM256_MAINLOOP(Asrc, Bsrc)

    // ---- epilogue: bias+relu -> bf16 tile in LDS, coalesced 16B stores ----
    // last phase ended with __syncthreads -> LDS free for reuse
    unsigned short* Ct = &lds[0][0][0];    // [256][256] shorts = 128 KB
    #pragma unroll
    for (int ni = 0; ni < 4; ++ni) {
        int col = wc * 64 + ni * 16 + ln;
        float bb = bias_cat[n0 + col];
        #pragma unroll
        for (int mi = 0; mi < 8; ++mi) {
            int row = wr * 128 + mi * 16 + qq * 4;
            #pragma unroll
            for (int r = 0; r < 4; ++r)
                Ct[(row + r) * 256 + col] = f2bf(fmaxf(acc[mi][ni][r] + bb, 0.f));
        }
    }
    __syncthreads();
    int w = nt >> 1, col0 = (nt & 1) * 256;
    unsigned short* outb = qkv + (size_t)(z * 3 + w) * 32768 * 512
                               + (size_t)mrow0 * 512 + col0;
    #pragma unroll
    for (int it = 0; it < 16; ++it) {
        int row = it * 16 + (tid >> 5);
        int ch = tid & 31;
        *reinterpret_cast<uint4*>(&outb[(size_t)row * 512 + ch * 8]) =
            *reinterpret_cast<const uint4*>(&Ct[row * 256 + ch * 8]);
    }
}

// ------- Kernel 3: score GEMM + tanh + row-sum (256^2 8-phase) -----------
// a[which][b][s] += sum_t tanh( A[s,:] . B[t,:] ),  A=k_self, B=q_other
__global__ __launch_bounds__(512, 2) void score_kernel(
    const unsigned short* __restrict__ qkv, float* __restrict__ a_out)
{
    __shared__ alignas(16) unsigned short lds[2][2][16384];  // 128 KB

    // bijective chunked XCD swizzle: 1024 blocks, 128/XCD, tt minor
    unsigned int fid = blockIdx.x;
    unsigned int swz = (fid & 7u) * 128u + (fid >> 3);
    int tt = swz & 3, st = (swz >> 2) & 3;
    int z = swz >> 4;
    int which = z >> 5, b = z & 31;

    const unsigned short* Asrc =
        qkv + ((size_t)(which ? 4 : 1) * 32768 + (size_t)b * 1024 + st * 256) * 512;
    const unsigned short* Bsrc =
        qkv + ((size_t)(which ? 0 : 3) * 32768 + (size_t)b * 1024 + tt * 256) * 512;

    int tid = threadIdx.x, lane = tid & 63, wv = tid >> 6;
    int wr = wv >> 2, wc = wv & 3;
    int qq = lane >> 4, ln = lane & 15;

    f32x4_t acc[8][4] = {};

    GEMM256_MAINLOOP(Asrc, Bsrc)

    // ---- epilogue: tanh, sum over wave's 64 t-cols, reduce, atomicAdd ----
    float* arow = a_out + (size_t)z * 1024 + st * 256 + wr * 128;
    #pragma unroll
    for (int mi = 0; mi < 8; ++mi) {
        #pragma unroll
        for (int r = 0; r < 4; ++r) {
            float s = 0.f;
            #pragma unroll
            for (int ni = 0; ni < 4; ++ni) s += fast_tanh(acc[mi][ni][r]);
            #pragma unroll
            for (int off = 1; off <= 8; off <<= 1) s += __shfl_xor(s, off, 64);
            if (ln == 0)
                atomicAdd(&arow[mi * 16 + qq * 4 + r], s);
        }
    }
}

// ---------------- Kernel 4: masked softmax over S=1024 -------------------
__global__ __launch_bounds__(256) void softmax_kernel(
    const float* __restrict__ a_in, const int* __restrict__ mask1,
    const int* __restrict__ mask2, float* __restrict__ w_out)
{
    int z = blockIdx.x, which = z >> 5, b = z & 31;
    const int* mask = (which ? mask2 : mask1) + (size_t)b * 1024;
    const float* a = a_in + (size_t)z * 1024;
    float* w = w_out + (size_t)z * 1024;
    int tid = threadIdx.x, lane = tid & 63, wv = tid >> 6;

    float vals[4];
    #pragma unroll
    for (int j = 0; j < 4; ++j) {
        int s = tid + j * 256;
        vals[j] = mask[s] ? -__builtin_inff() : a[s];
    }
    float m = fmaxf(fmaxf(vals[0], vals[1]), fmaxf(vals[2], vals[3]));
    #pragma unroll
    for (int off = 32; off; off >>= 1) m = fmaxf(m, __shfl_xor(m, off, 64));
    __shared__ float redm[4], redsum[4];
    if (lane == 0) redm[wv] = m;
    __syncthreads();
    m = fmaxf(fmaxf(redm[0], redm[1]), fmaxf(redm[2], redm[3]));

    float e[4], sum = 0.f;
    #pragma unroll
    for (int j = 0; j < 4; ++j) { e[j] = __expf(vals[j] - m); sum += e[j]; }
    #pragma unroll
    for (int off = 32; off; off >>= 1) sum += __shfl_xor(sum, off, 64);
    if (lane == 0) redsum[wv] = sum;
    __syncthreads();
    sum = redsum[0] + redsum[1] + redsum[2] + redsum[3];
    float inv = 1.f / sum;
    #pragma unroll
    for (int j = 0; j < 4; ++j) w[tid + j * 256] = e[j] * inv;
}

// --------- Kernel 5: acc[z][d] += sum_s w[s]*v[s,d]  (vectorized) --------
__global__ __launch_bounds__(128) void wsum_kernel(
    const unsigned short* __restrict__ qkv, const float* __restrict__ w_in,
    float* __restrict__ acc)
{
    int chunk = blockIdx.x;           // 0..7, 128 rows each
    int z = blockIdx.y, which = z >> 5, b = z & 31;
    const unsigned short* V =
        qkv + ((size_t)(which ? 5 : 2) * 32768 + (size_t)b * 1024) * 512;
    const float* w = w_in + (size_t)z * 1024;
    int d0 = threadIdx.x * 4;
    float a0 = 0.f, a1 = 0.f, a2 = 0.f, a3 = 0.f;
    int s0 = chunk * 128;
    #pragma unroll 4
    for (int s = s0; s < s0 + 128; ++s) {
        ushort4 v = *reinterpret_cast<const ushort4*>(&V[(size_t)s * 512 + d0]);
        float ws = w[s];
        a0 += ws * bf2f(v.x); a1 += ws * bf2f(v.y);
        a2 += ws * bf2f(v.z); a3 += ws * bf2f(v.w);
    }
    atomicAdd(&acc[(size_t)z * 512 + d0 + 0], a0);
    atomicAdd(&acc[(size_t)z * 512 + d0 + 1], a1);
    atomicAdd(&acc[(size_t)z * 512 + d0 + 2], a2);
    atomicAdd(&acc[(size_t)z * 512 + d0 + 3], a3);
}

// ---------------- Kernel 6: LayerNorm over D=512 -------------------------
__global__ __launch_bounds__(512) void ln_kernel(
    const float* __restrict__ acc, const float* __restrict__ gamma,
    const float* __restrict__ beta, float* __restrict__ out)
{
    int z = blockIdx.x, d = threadIdx.x;
    int lane = d & 63, wv = d >> 6;
    float x = acc[(size_t)z * 512 + d];
    float s = x;
    #pragma unroll
    for (int off = 32; off; off >>= 1) s += __shfl_xor(s, off, 64);
    __shared__ float red[8], red2[8];
    if (lane == 0) red[wv] = s;
    __syncthreads();
    float mu = 0.f;
    #pragma unroll
    for (int i = 0; i < 8; ++i) mu += red[i];
    mu *= (1.f / 512.f);
    float c = x - mu;
    float s2 = c * c;
    #pragma unroll
    for (int off = 32; off; off >>= 1) s2 += __shfl_xor(s2, off, 64);
    if (lane == 0) red2[wv] = s2;
    __syncthreads();
    float var = 0.f;
    #pragma unroll
    for (int i = 0; i < 8; ++i) var += red2[i];
    var *= (1.f / 512.f);
    out[(size_t)z * 512 + d] = c * __frsqrt_rn(var + 1e-5f) * gamma[d] + beta[d];
}

extern "C" void kernel_launch(void* const* d_in, const int* in_sizes, int n_in,
                              void* d_out, int out_size, void* d_ws, size_t ws_size,
                              hipStream_t stream) {
    const float* seq1 = (const float*)d_in[0];
    const float* seq2 = (const float*)d_in[1];
    const int* mask1 = (const int*)d_in[2];
    const int* mask2 = (const int*)d_in[3];
    const float* Wq = (const float*)d_in[4];
    const float* bq = (const float*)d_in[5];
    const float* Wk = (const float*)d_in[6];
    const float* bk = (const float*)d_in[7];
    const float* Wv = (const float*)d_in[8];
    const float* bv = (const float*)d_in[9];
    const float* gamma = (const float*)d_in[10];
    const float* beta = (const float*)d_in[11];
    float* out = (float*)d_out;

    char* ws = (char*)d_ws;
    float* a_sc = (float*)(ws);                              // 256 KB
    float* wsm = (float*)(ws + (256u << 10));                // 256 KB
    float* accv = (float*)(ws + (512u << 10));               // 128 KB
    float* bias_cat = (float*)(ws + (768u << 10));           // 6 KB
    unsigned short* Wt = (unsigned short*)(ws + (1u << 20)); // 1.5 MB
    unsigned short* Xb2 = (unsigned short*)(ws + (4ull << 20));   // 32 MB
    unsigned short* qkv = (unsigned short*)(ws + (40ull << 20));  // 192 MB
    unsigned short* Xb1 = (unsigned short*)d_in[1];  // reuse dead seq2 fp32 buf

    hipMemsetAsync(ws, 0, 640u << 10, stream);  // zero a_sc + wsm + accv

    wconv_kernel<<<dim3(8, 8, 3), 256, 0, stream>>>(Wq, Wk, Wv, Wt);
    biascat_kernel<<<1, 512, 0, stream>>>(bq, bk, bv, bias_cat);
    // seq2 first (reads d_in[1]); then seq1 overwrites d_in[1] with bf16 X1
    x2bf_kernel<<<dim3(8, 32), 256, 0, stream>>>(seq2, Xb2, accv + 32 * 512);
    x2bf_kernel<<<dim3(8, 32), 256, 0, stream>>>(seq1, Xb1, accv);
    qkv_gemm<<<dim3(1536), 512, 0, stream>>>(Xb1, Xb2, Wt, bias_cat, qkv);
    score_kernel<<<dim3(1024), 512, 0, stream>>>(qkv, a_sc);
    softmax_kernel<<<64, 256, 0, stream>>>(a_sc, mask1, mask2, wsm);
    wsum_kernel<<<dim3(8, 64), 128, 0, stream>>>(qkv, wsm, accv);
    ln_kernel<<<64, 512, 0, stream>>>(accv, gamma, beta, out);
}

// Round 3
// 436.735 us; speedup vs baseline: 1.1227x; 1.1227x over previous
//
#include <hip/hip_runtime.h>

// Workspace layout (~232 MiB):
//   [0, 256K)      a_scores  fp32 [2][32][1024]   (zeroed, atomic accum)
//   [256K, 512K)   softmax w fp32 [2][32][1024]
//   [512K, 640K)   acc       fp32 [2][32][512]    (zeroed; seqmean + vector)
//   [768K, 774K)   bias_cat  fp32 [1536]
//   [1M, 2.5M)     Wt bf16   [1536][512]  (Wt[w*512+n][k] = W_w[k][n])
//   [4M, 36M)      Xb2 bf16  [32768][512]  (seq2 converted)
//   [40M, 232M)    qkv bf16  [6][32768][512]  slots: q1,k1,v1,q2,k2,v2
// R1: XCD chunked swizzle -> FETCH 274->77MB, time flat (schedule-bound).
// R2: 256^2 8-phase port REGRESSED: (a) 1-bit LDS swizzle produced 16-way
//     conflicts (2.2e7), (b) quadrant phases re-read fragments (48KB/wave/
//     K-tile vs 24KB min) -> LDS-BW-bound at 25% MfmaUtil.
// R3: 3-bit slot swizzle (slot ^= row&7, both sides) + read-once quadrant
//     order Q00->Q01->Q11->Q10 holding A0/B0/B1 in registers. 24KB/wave/
//     tile -> LDS ceiling ~81% MfmaUtil; conflicts ~free.

typedef __bf16 bf16x8_t __attribute__((ext_vector_type(8)));
typedef float f32x4_t __attribute__((ext_vector_type(4)));

__device__ __forceinline__ unsigned short f2bf(float f) {
    union { float f; unsigned int u; } c; c.f = f;
    unsigned int u = c.u;
    unsigned int r = (u + 0x7FFFu + ((u >> 16) & 1u)) >> 16;  // RNE
    return (unsigned short)r;
}
__device__ __forceinline__ float bf2f(unsigned short h) {
    union { unsigned int u; float f; } c; c.u = ((unsigned int)h) << 16;
    return c.f;
}
__device__ __forceinline__ void gl2lds16(const void* g, void* l) {
    __builtin_amdgcn_global_load_lds(
        (const __attribute__((address_space(1))) void*)g,
        (__attribute__((address_space(3))) void*)l, 16, 0, 0);
}
__device__ __forceinline__ float fast_tanh(float x) {
    float e = __expf(2.f * x);                       // inf for large x -> tanh=1
    return 1.f - 2.f * __builtin_amdgcn_rcpf(e + 1.f);
}

// ---- 256x64 operand tile stage: 4 x global_load_lds(16B) per thread. ----
// LDS tile [256 rows][8 slots of 16B]. Swizzle: LDS[row][s] holds global
// slot s^(row&7) (involution). Dest is linear (wave-uniform + lane*16B);
// the SOURCE address carries the inverse swizzle (rule 21 / m201 pattern).
__device__ __forceinline__ void stage256(
    const unsigned short* __restrict__ src,  // already includes row0*512
    int k0, unsigned short* dstbase, int wv, int lane)
{
    #pragma unroll
    for (int l = 0; l < 4; ++l) {
        int idx = l * 512 + wv * 64 + lane;   // 0..2047
        int row = idx >> 3;                   // 0..255
        int slot = (idx & 7) ^ (row & 7);     // 3-bit slot XOR
        gl2lds16(&src[(size_t)row * 512 + k0 + slot * 8],
                 &dstbase[l * 4096 + wv * 512]);   // wave-uniform dest
    }
}

// ---- swizzled fragment reads (each fragment read ONCE per K-tile) ----
__device__ __forceinline__ void read_afrag(
    const unsigned short* buf, int rbase, int qq, int ln, bf16x8_t af[4][2])
{
    #pragma unroll
    for (int m = 0; m < 4; ++m) {
        int row = rbase + m * 16 + ln;
        #pragma unroll
        for (int ks = 0; ks < 2; ++ks) {
            int slot = (ks * 4 + qq) ^ (ln & 7);   // row&7 == ln&7 (rbase %16==0)
            af[m][ks] = *reinterpret_cast<const bf16x8_t*>(
                &buf[row * 64 + slot * 8]);
        }
    }
}
__device__ __forceinline__ void read_bfrag(
    const unsigned short* buf, int rbase, int qq, int ln, bf16x8_t bfr[2][2])
{
    #pragma unroll
    for (int n = 0; n < 2; ++n) {
        int row = rbase + n * 16 + ln;
        #pragma unroll
        for (int ks = 0; ks < 2; ++ks) {
            int slot = (ks * 4 + qq) ^ (ln & 7);
            bfr[n][ks] = *reinterpret_cast<const bf16x8_t*>(
                &buf[row * 64 + slot * 8]);
        }
    }
}
__device__ __forceinline__ void mfma_quad(
    const bf16x8_t a[4][2], const bf16x8_t b[2][2],
    f32x4_t acc[8][4], int mh, int nh)
{
    __builtin_amdgcn_s_setprio(1);
    #pragma unroll
    for (int m = 0; m < 4; ++m)
        #pragma unroll
        for (int n = 0; n < 2; ++n)
            #pragma unroll
            for (int ks = 0; ks < 2; ++ks)
                acc[mh * 4 + m][nh * 2 + n] =
                    __builtin_amdgcn_mfma_f32_16x16x32_bf16(
                        a[m][ks], b[n][ks], acc[mh * 4 + m][nh * 2 + n], 0, 0, 0);
    __builtin_amdgcn_s_setprio(0);
}

// 8-phase main loop over K=512 (8 tiles of BK=64, 2 per iteration).
// Per half: P1 read A0,B0 + stage nextA -> Q00; P2 read B1 + stage nextB
// -> Q01 (A0 held); P3 read A1 -> Q11 (B1 held); P4 -> Q10 (A1,B0 held);
// __syncthreads drains the stages (issued 3-4 phases earlier).
#define GEMM256_HALF(CUR, NXT, SA, SB)                                        \
    read_afrag(&lds[CUR][0][0], wr * 128, qq, ln, a0);                        \
    read_bfrag(&lds[CUR][1][0], wc * 64, qq, ln, b0);                         \
    SA;                                                                       \
    __builtin_amdgcn_s_barrier();                                             \
    mfma_quad(a0, b0, acc, 0, 0);                                             \
    __builtin_amdgcn_s_barrier();                                             \
    read_bfrag(&lds[CUR][1][0], wc * 64 + 32, qq, ln, b1);                    \
    SB;                                                                       \
    __builtin_amdgcn_s_barrier();                                             \
    mfma_quad(a0, b1, acc, 0, 1);                                             \
    __builtin_amdgcn_s_barrier();                                             \
    read_afrag(&lds[CUR][0][0], wr * 128 + 64, qq, ln, a1);                   \
    __builtin_amdgcn_s_barrier();                                             \
    mfma_quad(a1, b1, acc, 1, 1);                                             \
    __builtin_amdgcn_s_barrier();                                             \
    mfma_quad(a1, b0, acc, 1, 0);                                             \
    __syncthreads();

#define GEMM256_MAINLOOP(Asrc, Bsrc)                                          \
    stage256(Asrc, 0, &lds[0][0][0], wv, lane);                               \
    stage256(Bsrc, 0, &lds[0][1][0], wv, lane);                               \
    __syncthreads();                                                          \
    _Pragma("unroll")                                                         \
    for (int i = 0; i < 4; ++i) {                                             \
        int kO = (2 * i + 1) * 64;                                            \
        int kE = (2 * i + 2) * 64;                                            \
        bf16x8_t a0[4][2], a1[4][2], b0[2][2], b1[2][2];                      \
        GEMM256_HALF(0, 1,                                                    \
            stage256(Asrc, kO, &lds[1][0][0], wv, lane),                      \
            stage256(Bsrc, kO, &lds[1][1][0], wv, lane))                      \
        GEMM256_HALF(1, 0,                                                    \
            { if (i < 3) stage256(Asrc, kE, &lds[0][0][0], wv, lane); },      \
            { if (i < 3) stage256(Bsrc, kE, &lds[0][1][0], wv, lane); })      \
    }

// ---------------- Kernel 0: seq fp32 -> bf16, fused seq-mean -------------
__global__ __launch_bounds__(256) void x2bf_kernel(
    const float* __restrict__ src, unsigned short* __restrict__ dst,
    float* __restrict__ accv)
{
    int chunk = blockIdx.x;   // 0..7 (128 rows each)
    int b = blockIdx.y;       // 0..31
    int tid = threadIdx.x, lane = tid & 63, wv = tid >> 6;
    __shared__ float red[4][512];
    float sum[8] = {};
    size_t base = ((size_t)b * 1024 + (size_t)chunk * 128) * 512;
    #pragma unroll 4
    for (int i = 0; i < 32; ++i) {
        int r = i * 4 + wv;
        size_t ro = base + (size_t)r * 512;
        float4 a = *reinterpret_cast<const float4*>(&src[ro + lane * 4]);
        float4 c = *reinterpret_cast<const float4*>(&src[ro + 256 + lane * 4]);
        ushort4 ha; ha.x = f2bf(a.x); ha.y = f2bf(a.y); ha.z = f2bf(a.z); ha.w = f2bf(a.w);
        ushort4 hc; hc.x = f2bf(c.x); hc.y = f2bf(c.y); hc.z = f2bf(c.z); hc.w = f2bf(c.w);
        *reinterpret_cast<ushort4*>(&dst[ro + lane * 4]) = ha;
        *reinterpret_cast<ushort4*>(&dst[ro + 256 + lane * 4]) = hc;
        sum[0] += a.x; sum[1] += a.y; sum[2] += a.z; sum[3] += a.w;
        sum[4] += c.x; sum[5] += c.y; sum[6] += c.z; sum[7] += c.w;
    }
    #pragma unroll
    for (int t = 0; t < 4; ++t) {
        red[wv][lane * 4 + t] = sum[t];
        red[wv][256 + lane * 4 + t] = sum[4 + t];
    }
    __syncthreads();
    #pragma unroll
    for (int j = 0; j < 2; ++j) {
        int col = tid + j * 256;
        float s = red[0][col] + red[1][col] + red[2][col] + red[3][col];
        atomicAdd(&accv[(size_t)b * 512 + col], s * (1.f / 1024.f));
    }
}

// ---------------- Kernel 1: W [k][n] fp32 -> Wt [n][k] bf16 --------------
__global__ __launch_bounds__(256) void wconv_kernel(
    const float* __restrict__ Wq, const float* __restrict__ Wk,
    const float* __restrict__ Wv, unsigned short* __restrict__ Wt)
{
    const float* W = (blockIdx.z == 0) ? Wq : (blockIdx.z == 1) ? Wk : Wv;
    unsigned short* o = Wt + (size_t)blockIdx.z * 512 * 512;
    __shared__ unsigned short t[64][65];
    int k0 = blockIdx.x * 64, n0 = blockIdx.y * 64;
    #pragma unroll
    for (int i = 0; i < 16; ++i) {
        int idx = i * 256 + threadIdx.x;
        int r = idx >> 6, c = idx & 63;
        t[r][c] = f2bf(W[(size_t)(k0 + r) * 512 + n0 + c]);
    }
    __syncthreads();
    #pragma unroll
    for (int i = 0; i < 16; ++i) {
        int idx = i * 256 + threadIdx.x;
        int r = idx >> 6, c = idx & 63;   // r = n, c = k
        o[(size_t)(n0 + r) * 512 + k0 + c] = t[c][r];
    }
}

__global__ __launch_bounds__(512) void biascat_kernel(
    const float* __restrict__ bq, const float* __restrict__ bk,
    const float* __restrict__ bv, float* __restrict__ bc)
{
    int n = threadIdx.x;
    bc[n] = bq[n]; bc[512 + n] = bk[n]; bc[1024 + n] = bv[n];
}

// ------------- Kernel 2: QKV projection GEMM (256^2 8-phase) -------------
// C = relu(X @ [Wq|Wk|Wv] + b) -> bf16 slots. 8 waves 2Mx4N, 128x64/wave.
__global__ __launch_bounds__(512, 2) void qkv_gemm(
    const unsigned short* __restrict__ Xb1, const unsigned short* __restrict__ Xb2,
    const unsigned short* __restrict__ Wt, const float* __restrict__ bias_cat,
    unsigned short* __restrict__ qkv)
{
    __shared__ alignas(16) unsigned short lds[2][2][16384];  // 128 KB

    // bijective chunked XCD swizzle: 1536 blocks, 192/XCD, nt minor
    unsigned int fid = blockIdx.x;
    unsigned int swz = (fid & 7u) * 192u + (fid >> 3);
    int nt = swz % 6u;            // 0..5 (256-wide N tile)
    int mg = swz / 6u;            // 0..255
    int z = mg >> 7;              // which sequence
    int mrow0 = (mg & 127) * 256;
    int n0 = nt * 256;

    const unsigned short* Asrc = (z ? Xb2 : Xb1) + (size_t)mrow0 * 512;
    const unsigned short* Bsrc = Wt + (size_t)n0 * 512;

    int tid = threadIdx.x, lane = tid & 63, wv = tid >> 6;
    int wr = wv >> 2, wc = wv & 3;         // 2M x 4N wave grid
    int qq = lane >> 4, ln = lane & 15;

    f32x4_t acc[8][4] = {};

    GEMM256_MAINLOOP(Asrc, Bsrc)

    // ---- epilogue: bias+relu -> bf16 tile in LDS, coalesced 16B stores ----
    // last phase ended with __syncthreads -> LDS free for reuse
    unsigned short* Ct = &lds[0][0][0];    // [256][256] shorts = 128 KB
    #pragma unroll
    for (int ni = 0; ni < 4; ++ni) {
        int col = wc * 64 + ni * 16 + ln;
        float bb = bias_cat[n0 + col];
        #pragma unroll
        for (int mi = 0; mi < 8; ++mi) {
            int row = wr * 128 + mi * 16 + qq * 4;
            #pragma unroll
            for (int r = 0; r < 4; ++r)
                Ct[(row + r) * 256 + col] = f2bf(fmaxf(acc[mi][ni][r] + bb, 0.f));
        }
    }
    __syncthreads();
    int w = nt >> 1, col0 = (nt & 1) * 256;
    unsigned short* outb = qkv + (size_t)(z * 3 + w) * 32768 * 512
                               + (size_t)mrow0 * 512 + col0;
    #pragma unroll
    for (int it = 0; it < 16; ++it) {
        int row = it * 16 + (tid >> 5);
        int ch = tid & 31;
        *reinterpret_cast<uint4*>(&outb[(size_t)row * 512 + ch * 8]) =
            *reinterpret_cast<const uint4*>(&Ct[row * 256 + ch * 8]);
    }
}

// ------- Kernel 3: score GEMM + tanh + row-sum (256^2 8-phase) -----------
// a[which][b][s] += sum_t tanh( A[s,:] . B[t,:] ),  A=k_self, B=q_other
__global__ __launch_bounds__(512, 2) void score_kernel(
    const unsigned short* __restrict__ qkv, float* __restrict__ a_out)
{
    __shared__ alignas(16) unsigned short lds[2][2][16384];  // 128 KB

    // bijective chunked XCD swizzle: 1024 blocks, 128/XCD, tt minor
    unsigned int fid = blockIdx.x;
    unsigned int swz = (fid & 7u) * 128u + (fid >> 3);
    int tt = swz & 3, st = (swz >> 2) & 3;
    int z = swz >> 4;
    int which = z >> 5, b = z & 31;

    const unsigned short* Asrc =
        qkv + ((size_t)(which ? 4 : 1) * 32768 + (size_t)b * 1024 + st * 256) * 512;
    const unsigned short* Bsrc =
        qkv + ((size_t)(which ? 0 : 3) * 32768 + (size_t)b * 1024 + tt * 256) * 512;

    int tid = threadIdx.x, lane = tid & 63, wv = tid >> 6;
    int wr = wv >> 2, wc = wv & 3;
    int qq = lane >> 4, ln = lane & 15;

    f32x4_t acc[8][4] = {};

    GEMM256_MAINLOOP(Asrc, Bsrc)

    // ---- epilogue: tanh, sum over wave's 64 t-cols, reduce, atomicAdd ----
    float* arow = a_out + (size_t)z * 1024 + st * 256 + wr * 128;
    #pragma unroll
    for (int mi = 0; mi < 8; ++mi) {
        #pragma unroll
        for (int r = 0; r < 4; ++r) {
            float s = 0.f;
            #pragma unroll
            for (int ni = 0; ni < 4; ++ni) s += fast_tanh(acc[mi][ni][r]);
            #pragma unroll
            for (int off = 1; off <= 8; off <<= 1) s += __shfl_xor(s, off, 64);
            if (ln == 0)
                atomicAdd(&arow[mi * 16 + qq * 4 + r], s);
        }
    }
}

// ---------------- Kernel 4: masked softmax over S=1024 -------------------
__global__ __launch_bounds__(256) void softmax_kernel(
    const float* __restrict__ a_in, const int* __restrict__ mask1,
    const int* __restrict__ mask2, float* __restrict__ w_out)
{
    int z = blockIdx.x, which = z >> 5, b = z & 31;
    const int* mask = (which ? mask2 : mask1) + (size_t)b * 1024;
    const float* a = a_in + (size_t)z * 1024;
    float* w = w_out + (size_t)z * 1024;
    int tid = threadIdx.x, lane = tid & 63, wv = tid >> 6;

    float vals[4];
    #pragma unroll
    for (int j = 0; j < 4; ++j) {
        int s = tid + j * 256;
        vals[j] = mask[s] ? -__builtin_inff() : a[s];
    }
    float m = fmaxf(fmaxf(vals[0], vals[1]), fmaxf(vals[2], vals[3]));
    #pragma unroll
    for (int off = 32; off; off >>= 1) m = fmaxf(m, __shfl_xor(m, off, 64));
    __shared__ float redm[4], redsum[4];
    if (lane == 0) redm[wv] = m;
    __syncthreads();
    m = fmaxf(fmaxf(redm[0], redm[1]), fmaxf(redm[2], redm[3]));

    float e[4], sum = 0.f;
    #pragma unroll
    for (int j = 0; j < 4; ++j) { e[j] = __expf(vals[j] - m); sum += e[j]; }
    #pragma unroll
    for (int off = 32; off; off >>= 1) sum += __shfl_xor(sum, off, 64);
    if (lane == 0) redsum[wv] = sum;
    __syncthreads();
    sum = redsum[0] + redsum[1] + redsum[2] + redsum[3];
    float inv = 1.f / sum;
    #pragma unroll
    for (int j = 0; j < 4; ++j) w[tid + j * 256] = e[j] * inv;
}

// --------- Kernel 5: acc[z][d] += sum_s w[s]*v[s,d]  (vectorized) --------
__global__ __launch_bounds__(128) void wsum_kernel(
    const unsigned short* __restrict__ qkv, const float* __restrict__ w_in,
    float* __restrict__ acc)
{
    int chunk = blockIdx.x;           // 0..7, 128 rows each
    int z = blockIdx.y, which = z >> 5, b = z & 31;
    const unsigned short* V =
        qkv + ((size_t)(which ? 5 : 2) * 32768 + (size_t)b * 1024) * 512;
    const float* w = w_in + (size_t)z * 1024;
    int d0 = threadIdx.x * 4;
    float a0 = 0.f, a1 = 0.f, a2 = 0.f, a3 = 0.f;
    int s0 = chunk * 128;
    #pragma unroll 4
    for (int s = s0; s < s0 + 128; ++s) {
        ushort4 v = *reinterpret_cast<const ushort4*>(&V[(size_t)s * 512 + d0]);
        float ws = w[s];
        a0 += ws * bf2f(v.x); a1 += ws * bf2f(v.y);
        a2 += ws * bf2f(v.z); a3 += ws * bf2f(v.w);
    }
    atomicAdd(&acc[(size_t)z * 512 + d0 + 0], a0);
    atomicAdd(&acc[(size_t)z * 512 + d0 + 1], a1);
    atomicAdd(&acc[(size_t)z * 512 + d0 + 2], a2);
    atomicAdd(&acc[(size_t)z * 512 + d0 + 3], a3);
}

// ---------------- Kernel 6: LayerNorm over D=512 -------------------------
__global__ __launch_bounds__(512) void ln_kernel(
    const float* __restrict__ acc, const float* __restrict__ gamma,
    const float* __restrict__ beta, float* __restrict__ out)
{
    int z = blockIdx.x, d = threadIdx.x;
    int lane = d & 63, wv = d >> 6;
    float x = acc[(size_t)z * 512 + d];
    float s = x;
    #pragma unroll
    for (int off = 32; off; off >>= 1) s += __shfl_xor(s, off, 64);
    __shared__ float red[8], red2[8];
    if (lane == 0) red[wv] = s;
    __syncthreads();
    float mu = 0.f;
    #pragma unroll
    for (int i = 0; i < 8; ++i) mu += red[i];
    mu *= (1.f / 512.f);
    float c = x - mu;
    float s2 = c * c;
    #pragma unroll
    for (int off = 32; off; off >>= 1) s2 += __shfl_xor(s2, off, 64);
    if (lane == 0) red2[wv] = s2;
    __syncthreads();
    float var = 0.f;
    #pragma unroll
    for (int i = 0; i < 8; ++i) var += red2[i];
    var *= (1.f / 512.f);
    out[(size_t)z * 512 + d] = c * __frsqrt_rn(var + 1e-5f) * gamma[d] + beta[d];
}

extern "C" void kernel_launch(void* const* d_in, const int* in_sizes, int n_in,
                              void* d_out, int out_size, void* d_ws, size_t ws_size,
                              hipStream_t stream) {
    const float* seq1 = (const float*)d_in[0];
    const float* seq2 = (const float*)d_in[1];
    const int* mask1 = (const int*)d_in[2];
    const int* mask2 = (const int*)d_in[3];
    const float* Wq = (const float*)d_in[4];
    const float* bq = (const float*)d_in[5];
    const float* Wk = (const float*)d_in[6];
    const float* bk = (const float*)d_in[7];
    const float* Wv = (const float*)d_in[8];
    const float* bv = (const float*)d_in[9];
    const float* gamma = (const float*)d_in[10];
    const float* beta = (const float*)d_in[11];
    float* out = (float*)d_out;

    char* ws = (char*)d_ws;
    float* a_sc = (float*)(ws);                              // 256 KB
    float* wsm = (float*)(ws + (256u << 10));                // 256 KB
    float* accv = (float*)(ws + (512u << 10));               // 128 KB
    float* bias_cat = (float*)(ws + (768u << 10));           // 6 KB
    unsigned short* Wt = (unsigned short*)(ws + (1u << 20)); // 1.5 MB
    unsigned short* Xb2 = (unsigned short*)(ws + (4ull << 20));   // 32 MB
    unsigned short* qkv = (unsigned short*)(ws + (40ull << 20));  // 192 MB
    unsigned short* Xb1 = (unsigned short*)d_in[1];  // reuse dead seq2 fp32 buf

    hipMemsetAsync(ws, 0, 640u << 10, stream);  // zero a_sc + wsm + accv

    wconv_kernel<<<dim3(8, 8, 3), 256, 0, stream>>>(Wq, Wk, Wv, Wt);
    biascat_kernel<<<1, 512, 0, stream>>>(bq, bk, bv, bias_cat);
    // seq2 first (reads d_in[1]); then seq1 overwrites d_in[1] with bf16 X1
    x2bf_kernel<<<dim3(8, 32), 256, 0, stream>>>(seq2, Xb2, accv + 32 * 512);
    x2bf_kernel<<<dim3(8, 32), 256, 0, stream>>>(seq1, Xb1, accv);
    qkv_gemm<<<dim3(1536), 512, 0, stream>>>(Xb1, Xb2, Wt, bias_cat, qkv);
    score_kernel<<<dim3(1024), 512, 0, stream>>>(qkv, a_sc);
    softmax_kernel<<<64, 256, 0, stream>>>(a_sc, mask1, mask2, wsm);
    wsum_kernel<<<dim3(8, 64), 128, 0, stream>>>(qkv, wsm, accv);
    ln_kernel<<<64, 512, 0, stream>>>(accv, gamma, beta, out);
}